// Round 3
// baseline (70.979 us; speedup 1.0000x reference)
//
#include <hip/hip_runtime.h>

// DMLoss: chamfer-style polygon offset loss. N=256, P=128, TIME=10.
//
// R3: SINGLE dispatch. 256 blocks (1/CU) x 1024 threads (16 waves).
// - Item 1 analytic per-segment argmin (convex quadratic in t; evaluate the
//   two integer candidates around the vertex with REFERENCE-exact arithmetic:
//   s from a t/10.0f table, mul-add form), so values compared across segments
//   bitwise-match the reference's sampled values. Tie-breaks preserve
//   jnp.argmin first-occurrence (lower t, ascending p chunks, ascending q).
// - Both scans run back-to-back (independent) -> 2 barriers total in hot path.
// - Cross-block reduction fused in: each block publishes a float4 partial +
//   release flag into d_ws; block 0 spin-waits (agent-scope acquire) on the
//   256 flags and reduces. Flag init relies on documented harness behavior:
//   d_ws is re-poisoned to 0xAA before EVERY launch, so flags start != 1.

constexpr int N_ = 256;
constexpr int P_ = 128;

__device__ __forceinline__ float smooth_l1(float diff) {
  // BETA = 0.25: d<beta ? 0.5*d*d/beta : d - beta/2
  float a = fabsf(diff);
  return (a < 0.25f) ? (2.0f * a * a) : (a - 0.125f);
}

__global__ __launch_bounds__(1024) void dm_fused_kernel(
    const float* __restrict__ pred_c, const float* __restrict__ pred_o,
    const float* __restrict__ gt_c,  const float* __restrict__ gt_k,
    const int* __restrict__ mask,
    float* __restrict__ ws, float* __restrict__ out)
{
  const int n   = blockIdx.x;
  const int tid = threadIdx.x;       // 0..1023
  const int i   = tid & (P_ - 1);    // owned point / key index for scans
  const int q   = tid >> 7;          // 0..7: chunk of 16 segments/preds

  __shared__ float4 segAB[P_];       // a.x, a.y, b.x, b.y  (a=gt[p], b=gt[p-1])
  __shared__ float4 segEI[P_];       // e.x, e.y, 1/|e|^2, pad
  __shared__ float2 pc[P_];          // pred_contours[n]
  __shared__ float2 po[P_];          // pred_offsets[n]
  __shared__ float2 gk[P_];          // gt_key_points[n]
  __shared__ float2 stp[9];          // (t/10, (t+1)/10), t=0..8
  __shared__ float  st[10];          // t/10, t=0..9
  __shared__ float  bd1[8][P_];      // item1 per-chunk best dist
  __shared__ int    bj1[8][P_];      // item1 per-chunk best idx (p*10+t)
  __shared__ float  bd2[8][P_];      // item2 per-chunk best dist
  __shared__ int    bj2[8][P_];      // item2 per-chunk best idx
  __shared__ float4 redw[16];        // cross-wave reduction

  const float2* pc_g = (const float2*)pred_c + n * P_;
  const float2* po_g = (const float2*)pred_o + n * P_;
  const float2* gc_g = (const float2*)gt_c  + n * P_;
  const float2* gk_g = (const float2*)gt_k  + n * P_;

  // ---- staging (disjoint tid ranges) ----
  if (tid < P_) {
    int p = tid;
    float2 a = gc_g[p];
    float2 b = gc_g[(p + P_ - 1) & (P_ - 1)];   // roll by +1 => neighbor p-1
    segAB[p] = make_float4(a.x, a.y, b.x, b.y);
    float ex = a.x - b.x, ey = a.y - b.y;
    float e2 = ex * ex + ey * ey;
    segEI[p] = make_float4(ex, ey, (e2 > 0.0f) ? (1.0f / e2) : 0.0f, 0.0f);
  } else if (tid < 2 * P_) {
    pc[tid - P_] = pc_g[tid - P_];
  } else if (tid < 3 * P_) {
    po[tid - 2 * P_] = po_g[tid - 2 * P_];
  } else if (tid < 4 * P_) {
    gk[tid - 3 * P_] = gk_g[tid - 3 * P_];
  } else if (tid >= 512 && tid < 522) {
    int t = tid - 512;
    st[t] = (float)t / 10.0f;        // match reference f32 division rounding
  } else if (tid >= 544 && tid < 553) {
    int t = tid - 544;
    stp[t] = make_float2((float)t / 10.0f, (float)(t + 1) / 10.0f);
  }
  __syncthreads();

  // ===== item 1 scan: pred point i vs segments [q*16, q*16+16) =====
  const float2 pt = pc[i];
  float b1 = 3.0e38f; int j1 = 0;
  const int p0 = q * 16;
  #pragma unroll 4
  for (int p = p0; p < p0 + 16; ++p) {
    float4 ab = segAB[p];            // broadcast (p uniform per wave)
    float4 ei = segEI[p];
    float fx = ab.z - pt.x, fy = ab.w - pt.y;     // f = b - point
    float ef = ei.x * fx + ei.y * fy;
    float tf = -(ef * ei.z) * 10.0f;              // quadratic vertex, t-units
    int tl = min(max((int)floorf(tf), 0), 8);
    float2 ss = stp[tl];                          // (s_tl, s_tl+1), banks 0..19
    float ns0 = 1.0f - ss.x, ns1 = 1.0f - ss.y;
    float v0x = ab.x * ss.x + ab.z * ns0;
    float v0y = ab.y * ss.x + ab.w * ns0;
    float v1x = ab.x * ss.y + ab.z * ns1;
    float v1y = ab.y * ss.y + ab.w * ns1;
    float dx0 = pt.x - v0x, dy0 = pt.y - v0y;
    float dx1 = pt.x - v1x, dy1 = pt.y - v1y;
    float d0 = dx0 * dx0 + dy0 * dy0;
    float d1 = dx1 * dx1 + dy1 * dy1;
    bool c  = d1 < d0;                            // tie -> lower t
    float dl = c ? d1 : d0;
    int   jl = p * 10 + (c ? tl + 1 : tl);
    if (dl < b1) { b1 = dl; j1 = jl; }            // strict < => first occur.
  }
  bd1[q][i] = b1; bj1[q][i] = j1;

  // ===== item 2 scan: key point i vs pred points [q*16, q*16+16) =====
  const float2 kk = gk[i];
  float b2 = 3.0e38f; int j2 = 0;
  #pragma unroll 4
  for (int j = p0; j < p0 + 16; ++j) {
    float2 pp = pc[j];
    float dx = kk.x - pp.x, dy = kk.y - pp.y;
    float d = dx * dx + dy * dy;
    if (d < b2) { b2 = d; j2 = j; }
  }
  bd2[q][i] = b2; bj2[q][i] = j2;
  __syncthreads();

  // ===== parallel combines: threads 0-127 item1, 128-255 item2 =====
  float s1 = 0.0f, c1 = 0.0f, s2 = 0.0f, c2 = 0.0f;
  if (tid < P_) {
    const int t = tid;
    float bb = bd1[0][t]; int jj = bj1[0][t];
    #pragma unroll
    for (int w = 1; w < 8; ++w) {
      float d = bd1[w][t];
      if (d < bb) { bb = d; jj = bj1[w][t]; }     // ascending q => lower j ties
    }
    if (bb <= 1.0e6f) {                           // BOUND2
      int p = jj / 10, tt = jj - (jj / 10) * 10;
      float4 ab = segAB[p];
      float s = st[tt], ns = 1.0f - s;
      float vx = ab.x * s + ab.z * ns;
      float vy = ab.y * s + ab.w * ns;
      float2 pl = pc[t];
      float2 o  = po[t];
      float tx = (vx - pl.x) * 0.25f;             // / STRIDE
      float ty = (vy - pl.y) * 0.25f;
      s1 = smooth_l1(o.x - tx) + smooth_l1(o.y - ty);
      c1 = 1.0f;
    }
  } else if (tid < 2 * P_) {
    const int t = tid - P_;
    float bb = bd2[0][t]; int jj = bj2[0][t];
    #pragma unroll
    for (int w = 1; w < 8; ++w) {
      float d = bd2[w][t];
      if (d < bb) { bb = d; jj = bj2[w][t]; }
    }
    if (bb <= 1.0e6f && mask[n * P_ + t] != 0) {
      float2 pp = pc[jj];
      float2 o  = po[jj];
      float2 kv = gk[t];
      float tx = (kv.x - pp.x) * 0.25f;
      float ty = (kv.y - pp.y) * 0.25f;
      s2 = smooth_l1(o.x - tx) + smooth_l1(o.y - ty);
      c2 = 1.0f;
    }
  }

  // ===== block reduction over 16 waves =====
  #pragma unroll
  for (int off = 32; off > 0; off >>= 1) {
    s1 += __shfl_down(s1, off);
    c1 += __shfl_down(c1, off);
    s2 += __shfl_down(s2, off);
    c2 += __shfl_down(c2, off);
  }
  const int wave = tid >> 6;
  const int lane = tid & 63;
  if (lane == 0) redw[wave] = make_float4(s1, c1, s2, c2);
  __syncthreads();

  float4* partial = (float4*)ws;                       // 256 * 16 B
  unsigned* flags = (unsigned*)(ws + 4 * N_);          // 256 * 4 B after that
  if (tid == 0) {
    float4 r = redw[0];
    #pragma unroll
    for (int w = 1; w < 16; ++w) {
      float4 v = redw[w];
      r.x += v.x; r.y += v.y; r.z += v.z; r.w += v.w;
    }
    float* p4 = (float*)&partial[n];
    __hip_atomic_store(p4 + 0, r.x, __ATOMIC_RELAXED, __HIP_MEMORY_SCOPE_AGENT);
    __hip_atomic_store(p4 + 1, r.y, __ATOMIC_RELAXED, __HIP_MEMORY_SCOPE_AGENT);
    __hip_atomic_store(p4 + 2, r.z, __ATOMIC_RELAXED, __HIP_MEMORY_SCOPE_AGENT);
    __hip_atomic_store(p4 + 3, r.w, __ATOMIC_RELAXED, __HIP_MEMORY_SCOPE_AGENT);
    __hip_atomic_store(&flags[n], 1u, __ATOMIC_RELEASE, __HIP_MEMORY_SCOPE_AGENT);
  }

  // ===== block 0: spin on all 256 flags, reduce, write scalar =====
  if (blockIdx.x == 0) {
    float fs1 = 0.0f, fc1 = 0.0f, fs2 = 0.0f, fc2 = 0.0f;
    if (tid < N_) {
      // poison 0xAAAAAAAA != 1u, set to 1u by each block's release store
      while (__hip_atomic_load(&flags[tid], __ATOMIC_ACQUIRE,
                               __HIP_MEMORY_SCOPE_AGENT) != 1u) {
        __builtin_amdgcn_s_sleep(1);
      }
      const float* p4 = (const float*)&partial[tid];
      fs1 = __hip_atomic_load(p4 + 0, __ATOMIC_RELAXED, __HIP_MEMORY_SCOPE_AGENT);
      fc1 = __hip_atomic_load(p4 + 1, __ATOMIC_RELAXED, __HIP_MEMORY_SCOPE_AGENT);
      fs2 = __hip_atomic_load(p4 + 2, __ATOMIC_RELAXED, __HIP_MEMORY_SCOPE_AGENT);
      fc2 = __hip_atomic_load(p4 + 3, __ATOMIC_RELAXED, __HIP_MEMORY_SCOPE_AGENT);
    }
    #pragma unroll
    for (int off = 32; off > 0; off >>= 1) {
      fs1 += __shfl_down(fs1, off);
      fc1 += __shfl_down(fc1, off);
      fs2 += __shfl_down(fs2, off);
      fc2 += __shfl_down(fc2, off);
    }
    if (lane == 0) redw[wave] = make_float4(fs1, fc1, fs2, fc2);
    __syncthreads();
    if (tid == 0) {
      float4 r = redw[0];
      #pragma unroll
      for (int w = 1; w < 16; ++w) {   // waves 4..15 contributed zeros
        float4 v = redw[w];
        r.x += v.x; r.y += v.y; r.z += v.z; r.w += v.w;
      }
      // masked means: sum / max(2*count, 1), each weighted 0.5 (KEY_W)
      float l1 = (r.x / fmaxf(r.y * 2.0f, 1.0f)) * 0.5f;
      float l2 = (r.z / fmaxf(r.w * 2.0f, 1.0f)) * 0.5f;
      out[0] = l1 + l2;
    }
  }
}

extern "C" void kernel_launch(void* const* d_in, const int* in_sizes, int n_in,
                              void* d_out, int out_size, void* d_ws, size_t ws_size,
                              hipStream_t stream) {
  const float* pred_c = (const float*)d_in[0];   // pred_contours (256,128,2)
  const float* pred_o = (const float*)d_in[1];   // pred_offsets  (256,128,2)
  const float* gt_c   = (const float*)d_in[2];   // gt_contours   (256,128,2)
  const float* gt_k   = (const float*)d_in[3];   // gt_key_points (256,128,2)
  const int*   mask   = (const int*)d_in[4];     // gt_key_points_mask (256,128)

  dm_fused_kernel<<<N_, 1024, 0, stream>>>(pred_c, pred_o, gt_c, gt_k, mask,
                                           (float*)d_ws, (float*)d_out);
}